// Round 11
// baseline (121.943 us; speedup 1.0000x reference)
//
#include <hip/hip_runtime.h>
#include <math.h>

#define N_IN 256
#define BATCH 4096
#define GRID 512
#define BLOCK 256
#define NROWS (BATCH * N_IN * 4)          // 4,194,304 float4 rows
#define STRIDE (GRID * BLOCK)             // 131072 rows = 32768 matrices ≡ 0 mod 256
#define ITERS (NROWS / STRIDE)            // = 32, compile-time

typedef float f32x4 __attribute__((ext_vector_type(4)));  // native vec type:
// __builtin_nontemporal_* requires scalar/native-vector pointee (HIP_vector_type fails).

// ---------------------------------------------------------------------------
// Single fused kernel. One float4 row per thread per iteration.
// n = (idx0>>2)&255 is LOOP-INVARIANT -> WM[n] built once per thread in
// registers (f64 Rodrigues, formula identical to all passing rounds).
// Non-temporal load/store (`nt` modifier): the 128 MiB I/O stream has zero
// L2 reuse (256 MiB touched vs 32 MiB L2, lines dead after one touch), so
// bypassing L2 allocation removes write-allocate tag/fill overhead.
// Hot loop: 1 nt global_load_dwordx4 + ~12 v_fma_f32 + 1 nt
// global_store_dwordx4 per 32 B HBM — copy-equivalent VMEM profile.
// ---------------------------------------------------------------------------
__global__ __launch_bounds__(BLOCK) void fused_wm_apply_kernel(
        const f32x4* __restrict__ I,
        const float* __restrict__ aW,
        const float* __restrict__ uW,
        const float* __restrict__ tW,
        f32x4* __restrict__ O) {
    int idx0 = blockIdx.x * BLOCK + threadIdx.x;
    int n = (idx0 >> 2) & (N_IN - 1);     // loop-invariant matrix id

    // --- build WM[n] in registers (identical f64 math to prior rounds) ---
    double a = (double)aW[n];
    double u0 = 1.0 / (1.0 + exp(-(double)uW[n * 3 + 0]));
    double u1 = 1.0 / (1.0 + exp(-(double)uW[n * 3 + 1]));
    double u2 = 1.0 / (1.0 + exp(-(double)uW[n * 3 + 2]));
    double inv_norm = 1.0 / sqrt(u0 * u0 + u1 * u1 + u2 * u2);
    double ux = u0 * inv_norm, uy = u1 * inv_norm, uz = u2 * inv_norm;
    double sa = sin(a), ca = cos(a);

    float w0x = (float)((1.0 - ux * ux) * ca + ux * ux);
    float w0y = (float)(-uz * sa - ux * uy * ca + ux * uy);
    float w0z = (float)( uy * sa - ux * uz * ca + ux * uz);
    float w0w = tW[n * 3 + 0];
    float w1x = (float)( uz * sa - uy * ux * ca + uy * ux);
    float w1y = (float)((1.0 - uy * uy) * ca + uy * uy);
    float w1z = (float)(-ux * sa - uy * uz * ca + uy * uz);
    float w1w = tW[n * 3 + 1];
    float w2x = (float)(-uy * sa - uz * ux * ca + uz * ux);
    float w2y = (float)( ux * sa - uz * uy * ca + uz * uy);
    float w2z = (float)((1.0 - uz * uz) * ca + uz * uz);
    float w2w = tW[n * 3 + 2];
    // row 3 of WM is [0,0,0,1] — folded into the FMAs below.

    // --- streaming apply: out_row = I_row (1x4) @ WM (4x4) ---
    #pragma unroll 8
    for (int it = 0; it < ITERS; ++it) {
        int idx = idx0 + it * STRIDE;
        f32x4 r = __builtin_nontemporal_load(&I[idx]);
        f32x4 o;
        o.x = r.x * w0x + r.y * w1x + r.z * w2x;           // + r.w * 0
        o.y = r.x * w0y + r.y * w1y + r.z * w2y;           // + r.w * 0
        o.z = r.x * w0z + r.y * w1z + r.z * w2z;           // + r.w * 0
        o.w = r.x * w0w + r.y * w1w + r.z * w2w + r.w;     // + r.w * 1
        __builtin_nontemporal_store(o, &O[idx]);
    }
}

extern "C" void kernel_launch(void* const* d_in, const int* in_sizes, int n_in,
                              void* d_out, int out_size, void* d_ws, size_t ws_size,
                              hipStream_t stream) {
    const float* I  = (const float*)d_in[0];   // (4096, 256, 4, 4)
    const float* aW = (const float*)d_in[1];   // (256, 1, 1)
    const float* uW = (const float*)d_in[2];   // (256, 1, 3)
    const float* tW = (const float*)d_in[3];   // (256, 1, 3)
    float* out = (float*)d_out;

    fused_wm_apply_kernel<<<GRID, BLOCK, 0, stream>>>(
        (const f32x4*)I, aW, uW, tW, (f32x4*)out);
}